// Round 8
// baseline (229.281 us; speedup 1.0000x reference)
//
#include <hip/hip_runtime.h>

#define N_NODES 100000
#define N_EDGES 3200000
#define IN_DIM  29
#define HID_DIM 64
#define NBUCK   782            // ceil(N / 128)
#define BNODES  128            // dst nodes per bucket
#define CAP     5120           // slots/bucket; mean 4092, sigma ~64 -> +16 sigma
#define EPT     8
#define EPB     4096           // 512 threads * 8 edges

// ---- ws layout (4-byte units) ---------------------------------------------
#define OFF_CUR   0            // gcursor[NBUCK] (sizes; region b starts at b*CAP)
#define OFF_ROWS  1024         // rowStart[N]
#define OFF_ROWE  101024       // rowEnd[N]
#define OFF_DINV  201024       // dinv[N]
#define OFF_ZS    301024       // zs[2N]
#define OFF_EBUF  501024       // ebuf[NBUCK*CAP] = 4,003,840
#define OFF_XS    4504864      // xs bf16[32N] = 16N uints, 128B aligned

static __device__ __forceinline__ unsigned short f2bf(float f) {
    unsigned u = __float_as_uint(f);
    u += 0x7fffu + ((u >> 16) & 1u);   // RNE
    return (unsigned short)(u >> 16);
}

static __device__ __forceinline__ void unpack_add(float4& acc, uint2 a) {
    acc.x += __uint_as_float(a.x << 16);
    acc.y += __uint_as_float(a.x & 0xFFFF0000u);
    acc.z += __uint_as_float(a.y << 16);
    acc.w += __uint_as_float(a.y & 0xFFFF0000u);
}

// ---------------- partition: bucket edges by dst>>7, packed src|dl<<17 ------
__global__ __launch_bounds__(512) void partition_kernel(const int* __restrict__ ei,
        int* __restrict__ gcursor, int* __restrict__ ebuf) {
    __shared__ int lhist[NBUCK];
    __shared__ int lcur[NBUCK];
    int tid = threadIdx.x;
    for (int i = tid; i < NBUCK; i += 512) lhist[i] = 0;
    __syncthreads();

    int base = blockIdx.x * EPB + tid * EPT;     // 8-aligned; never straddles E
    int dv[EPT], sv[EPT];
    bool valid = (base < N_EDGES);
    if (valid) {
        const int4* dp = (const int4*)(ei + N_EDGES + base);
        const int4* sp = (const int4*)(ei + base);
        #pragma unroll
        for (int q = 0; q < 2; ++q) {
            int4 t = dp[q];
            dv[4*q+0] = t.x; dv[4*q+1] = t.y; dv[4*q+2] = t.z; dv[4*q+3] = t.w;
            int4 u = sp[q];
            sv[4*q+0] = u.x; sv[4*q+1] = u.y; sv[4*q+2] = u.z; sv[4*q+3] = u.w;
        }
        #pragma unroll
        for (int j = 0; j < EPT; ++j) atomicAdd(&lhist[dv[j] >> 7], 1);
    }
    __syncthreads();
    for (int i = tid; i < NBUCK; i += 512) {
        int c = lhist[i];
        lcur[i] = c ? (atomicAdd(&gcursor[i], c) + i * CAP) : 0;  // claim base
    }
    __syncthreads();
    if (valid) {
        #pragma unroll
        for (int j = 0; j < EPT; ++j) {
            int d = dv[j];
            int pos = atomicAdd(&lcur[d >> 7], 1);     // LDS cursor
            ebuf[pos] = sv[j] | ((d & 127) << 17);     // src < 2^17, dl 7 bits
        }
    }
}

// ---- per-bucket exact counting sort in LDS + rowStart/rowEnd/dinv/xs -------
__global__ __launch_bounds__(512) void bucketsort_kernel(const int* __restrict__ gcursor,
        int* __restrict__ ebuf, int* __restrict__ rowStart, int* __restrict__ rowEnd,
        float* __restrict__ dinv, const float* __restrict__ x,
        unsigned int* __restrict__ xsb) {
    __shared__ int   cnt[BNODES];
    __shared__ int   cur[BNODES];
    __shared__ float dls[BNODES];
    __shared__ int   stage[CAP];                       // 20 KB
    int b = blockIdx.x, tid = threadIdx.x;
    if (tid < BNODES) cnt[tid] = 0;
    __syncthreads();
    int base = b * CAP;
    int size = gcursor[b];

    for (int j = tid; j < size; j += 512)              // pass 1: count
        atomicAdd(&cnt[((unsigned)ebuf[base + j]) >> 17], 1);
    __syncthreads();

    if (tid < 64) {                                    // wave-0 scan of 128 bins
        int a = cnt[2 * tid], bb = cnt[2 * tid + 1];
        int s = a + bb;
        int incl = s;
        #pragma unroll
        for (int off = 1; off < 64; off <<= 1) {
            int t = __shfl_up(incl, off);
            if ((int)tid >= off) incl += t;
        }
        int excl = incl - s;                           // exclusive before 2*tid
        cur[2 * tid]     = excl;
        cur[2 * tid + 1] = excl + a;
    }
    __syncthreads();

    if (tid < BNODES) {
        int v = cnt[tid];
        int excl = cur[tid];
        int node = b * BNODES + tid;
        if (node < N_NODES) {
            rowStart[node] = base + excl;
            rowEnd[node]   = base + excl + v;
            float dn = rsqrtf((float)v + 1.0f);        // +1 = self loop
            dinv[node] = dn;
            dls[tid] = dn;
        }
    }
    __syncthreads();

    for (int j = tid; j < size; j += 512) {            // pass 2: place into LDS
        unsigned p = (unsigned)ebuf[base + j];
        int pos = atomicAdd(&cur[p >> 17], 1);
        stage[pos] = p & 0x1FFFF;
    }
    __syncthreads();
    for (int j = tid; j < size; j += 512)              // coalesced writeback
        ebuf[base + j] = stage[j];

    // xs = bf16(x * dinv), padded to 32 features; 2 features per uint
    for (int i = tid; i < BNODES * 16; i += 512) {
        int dl = i >> 4, kp = i & 15;                  // features 2kp, 2kp+1
        int nd = b * BNODES + dl;
        if (nd < N_NODES) {
            float dn = dls[dl];
            int k0 = kp * 2, k1 = k0 + 1;
            float f0 = (k0 < IN_DIM) ? x[nd * IN_DIM + k0] * dn : 0.0f;
            float f1 = (k1 < IN_DIM) ? x[nd * IN_DIM + k1] * dn : 0.0f;
            unsigned u = (unsigned)f2bf(f0) | ((unsigned)f2bf(f1) << 16);
            xsb[(size_t)nd * 16 + kp] = u;
        }
    }
}

// --- fused: per-node gather (8 streams, bf16, MASKED unroll-4) + MLP --------
__global__ __launch_bounds__(256) void fused_kernel(const unsigned int* __restrict__ xs_,
        const int* __restrict__ rowStart, const int* __restrict__ rowEnd,
        const int* __restrict__ ebuf, const float* __restrict__ dinv,
        const float* __restrict__ W1, const float* __restrict__ b1,
        const float* __restrict__ W2, float* __restrict__ zs) {
    __shared__ float w1s[IN_DIM * HID_DIM];
    __shared__ float b1s[HID_DIM];
    __shared__ float w2s[HID_DIM * 2];
    int tid = threadIdx.x;
    for (int i = tid; i < IN_DIM * HID_DIM; i += 256) w1s[i] = W1[i];
    if (tid < HID_DIM) {
        b1s[tid] = b1[tid];
        w2s[tid * 2 + 0] = W2[tid * 2 + 0];
        w2s[tid * 2 + 1] = W2[tid * 2 + 1];
    }
    __syncthreads();

    int lane = tid & 63;
    int q = lane >> 3, m = lane & 7;                   // 8 streams x 8 lanes
    const uint2* xsb = (const uint2*)xs_;              // row = 8 uint2 (64 B)
    int nodeBase = blockIdx.x * 16 + (tid >> 6) * 4;   // 4 nodes per wave

    for (int rep = 0; rep < 4; ++rep) {
        int node = nodeBase + rep;
        if (node >= N_NODES) break;

        float4 acc = make_float4(0.f, 0.f, 0.f, 0.f);
        if (q == 0)                                    // self loop in stream 0
            unpack_add(acc, xsb[(size_t)node * 8 + m]);

        int rs = rowStart[node], re = rowEnd[node];
        int last = re - 1;
        for (int j = rs + q; j < re; j += 32) {        // masked: always 4 in flight
            int j1 = j + 8, j2 = j + 16, j3 = j + 24;
            int s0 = ebuf[j];
            int s1 = ebuf[min(j1, last)];
            int s2 = ebuf[min(j2, last)];
            int s3 = ebuf[min(j3, last)];
            uint2 a  = xsb[(size_t)s0 * 8 + m];
            uint2 bb = xsb[(size_t)s1 * 8 + m];
            uint2 c  = xsb[(size_t)s2 * 8 + m];
            uint2 d  = xsb[(size_t)s3 * 8 + m];
            unpack_add(acc, a);
            if (j1 < re) unpack_add(acc, bb);
            if (j2 < re) unpack_add(acc, c);
            if (j3 < re) unpack_add(acc, d);
        }
        #pragma unroll
        for (int msk = 8; msk <= 32; msk <<= 1) {      // fold 8 streams
            acc.x += __shfl_xor(acc.x, msk);
            acc.y += __shfl_xor(acc.y, msk);
            acc.z += __shfl_xor(acc.z, msk);
            acc.w += __shfl_xor(acc.w, msk);
        }
        float dn = dinv[node];
        acc.x *= dn; acc.y *= dn; acc.z *= dn; acc.w *= dn;

        float h = b1s[lane];
        #pragma unroll
        for (int kk = 0; kk < IN_DIM; ++kk) {          // comp pick compile-time
            float comp = ((kk & 3) == 0) ? acc.x : ((kk & 3) == 1) ? acc.y
                       : ((kk & 3) == 2) ? acc.z : acc.w;
            h = fmaf(__shfl(comp, kk >> 2), w1s[kk * HID_DIM + lane], h);
        }
        h = fmaxf(h, 0.0f);

        float z0 = h * w2s[lane * 2 + 0];
        float z1 = h * w2s[lane * 2 + 1];
        #pragma unroll
        for (int off = 32; off > 0; off >>= 1) {
            z0 += __shfl_down(z0, off);
            z1 += __shfl_down(z1, off);
        }
        if (lane == 0) {                               // pre-scale by src dinv
            zs[node * 2 + 0] = z0 * dn;
            zs[node * 2 + 1] = z1 * dn;
        }
    }
}

// ------- agg2: 16-lane group per node, masked unroll-2 + finalize -----------
__global__ __launch_bounds__(256) void agg2_kernel(const float* __restrict__ zs,
        const int* __restrict__ rowStart, const int* __restrict__ rowEnd,
        const int* __restrict__ ebuf, const float* __restrict__ dinv,
        const float* __restrict__ b2, float* __restrict__ out) {
    int tid = threadIdx.x;
    int node = blockIdx.x * 16 + (tid >> 4);
    if (node >= N_NODES) return;
    int gl = tid & 15;
    const float2* zs2 = (const float2*)zs;
    float a0 = 0.0f, a1 = 0.0f, c0 = 0.0f, c1 = 0.0f;
    int rs = rowStart[node], re = rowEnd[node];
    int last = re - 1;
    for (int j = rs + gl; j < re; j += 32) {           // masked: 2 in flight
        int j1 = j + 16;
        float2 za = zs2[ebuf[j]];
        float2 zb = zs2[ebuf[min(j1, last)]];
        a0 += za.x; a1 += za.y;
        if (j1 < re) { c0 += zb.x; c1 += zb.y; }
    }
    a0 += c0; a1 += c1;
    a0 += __shfl_xor(a0, 8); a1 += __shfl_xor(a1, 8);
    a0 += __shfl_xor(a0, 4); a1 += __shfl_xor(a1, 4);
    a0 += __shfl_xor(a0, 2); a1 += __shfl_xor(a1, 2);
    a0 += __shfl_xor(a0, 1); a1 += __shfl_xor(a1, 1);
    if (gl == 0) {
        float dn = dinv[node];
        float2 zself = zs2[node];
        float2 o;
        o.x = dn * (a0 + zself.x) + b2[0];
        o.y = dn * (a1 + zself.y) + b2[1];
        ((float2*)out)[node] = o;
    }
}

extern "C" void kernel_launch(void* const* d_in, const int* in_sizes, int n_in,
                              void* d_out, int out_size, void* d_ws, size_t ws_size,
                              hipStream_t stream) {
    const float* x  = (const float*)d_in[0];
    const int*   ei = (const int*)d_in[1];
    const float* W1 = (const float*)d_in[2];
    const float* b1 = (const float*)d_in[3];
    const float* W2 = (const float*)d_in[4];
    const float* b2 = (const float*)d_in[5];
    float* out = (float*)d_out;

    int*   wsi      = (int*)d_ws;
    float* wsf      = (float*)d_ws;
    int*   gcursor  = wsi + OFF_CUR;
    int*   rowStart = wsi + OFF_ROWS;
    int*   rowEnd   = wsi + OFF_ROWE;
    float* dinv     = wsf + OFF_DINV;
    float* zs       = wsf + OFF_ZS;
    int*   ebuf     = wsi + OFF_EBUF;
    unsigned int* xsb = (unsigned int*)(wsi + OFF_XS);

    hipMemsetAsync(gcursor, 0, NBUCK * sizeof(int), stream);
    partition_kernel<<<(N_EDGES + EPB - 1) / EPB, 512, 0, stream>>>(ei, gcursor, ebuf);
    bucketsort_kernel<<<NBUCK, 512, 0, stream>>>(gcursor, ebuf, rowStart, rowEnd, dinv, x, xsb);
    fused_kernel<<<(N_NODES + 15) / 16, 256, 0, stream>>>(xsb, rowStart, rowEnd, ebuf, dinv, W1, b1, W2, zs);
    agg2_kernel<<<(N_NODES + 15) / 16, 256, 0, stream>>>(zs, rowStart, rowEnd, ebuf, dinv, b2, out);
}